// Round 8
// baseline (218.455 us; speedup 1.0000x reference)
//
#include <hip/hip_runtime.h>
#include <hip/hip_bf16.h>
#include <stdint.h>

typedef __bf16 bf16_t;
typedef __bf16 bf16x8 __attribute__((ext_vector_type(8)));
typedef __bf16 bf16x4 __attribute__((ext_vector_type(4)));
typedef float f32x4 __attribute__((ext_vector_type(4)));

#define GLD_LDS16(src, dst)                                                              \
  __builtin_amdgcn_global_load_lds((const __attribute__((address_space(1))) void*)(src), \
                                   (__attribute__((address_space(3))) void*)(dst), 16, 0, 0)

// ---------------------------------------------------------------------------
// fp32 -> bf16 convert, ALL tensors in one launch. blockIdx.y = segment.
// ---------------------------------------------------------------------------
struct CvtArgs {
  const float* src[7];
  bf16_t* dst[7];
  long n4[7];
};

__global__ __launch_bounds__(256) void cvt_all(CvtArgs a) {
  const int seg = blockIdx.y;
  const float* __restrict__ in = a.src[seg];
  bf16_t* __restrict__ out = a.dst[seg];
  const long n4 = a.n4[seg];
  long i = (long)blockIdx.x * blockDim.x + threadIdx.x;
  const long stride = (long)gridDim.x * blockDim.x;
  for (; i < n4; i += stride) {
    float4 v = ((const float4*)in)[i];
    bf16x4 o;
    o[0] = (bf16_t)v.x; o[1] = (bf16_t)v.y; o[2] = (bf16_t)v.z; o[3] = (bf16_t)v.w;
    ((bf16x4*)out)[i] = o;
  }
}

// ---------------------------------------------------------------------------
// Causal row softmax, in-place, bounded: row i only touches
// j < jmax = (floor(i/128)+1)*128 (PV's KBOUND never reads past jmax).
// ---------------------------------------------------------------------------
__global__ __launch_bounds__(256) void softmax_causal(bf16_t* __restrict__ S, int n, long sB) {
  const int i = blockIdx.x;
  const int z = blockIdx.y;
  bf16_t* row = S + (long)z * sB + (long)i * n;
  const int t = threadIdx.x;
  const int j0 = t << 3;
  const int jmax = ((i >> 7) + 1) << 7;
  const bool active = j0 < jmax;

  float vals[8];
  float mx = -3.0e38f;
  if (active) {
    bf16x8 vv = ((const bf16x8*)row)[t];
#pragma unroll
    for (int e = 0; e < 8; ++e) {
      float v = (j0 + e <= i) ? (float)vv[e] : -3.0e38f;
      vals[e] = v;
      mx = fmaxf(mx, v);
    }
  }
#pragma unroll
  for (int off = 32; off; off >>= 1) mx = fmaxf(mx, __shfl_xor(mx, off));
  __shared__ float redm[4];
  if ((t & 63) == 0) redm[t >> 6] = mx;
  __syncthreads();
  mx = fmaxf(fmaxf(redm[0], redm[1]), fmaxf(redm[2], redm[3]));

  float sum = 0.f;
  if (active) {
#pragma unroll
    for (int e = 0; e < 8; ++e) {
      float p = (j0 + e <= i) ? __expf(vals[e] - mx) : 0.f;
      vals[e] = p;
      sum += p;
    }
  }
#pragma unroll
  for (int off = 32; off; off >>= 1) sum += __shfl_xor(sum, off);
  __shared__ float reds[4];
  if ((t & 63) == 0) reds[t >> 6] = sum;
  __syncthreads();
  sum = reds[0] + reds[1] + reds[2] + reds[3];
  const float inv = 1.0f / sum;

  if (active) {
    bf16x8 o;
#pragma unroll
    for (int e = 0; e < 8; ++e) o[e] = (bf16_t)(vals[e] * inv);
    ((bf16x8*)row)[t] = o;
  }
}

// ---------------------------------------------------------------------------
// XCD-chunked bijective remap (requires nwg % 8 == 0; all grids comply).
// ---------------------------------------------------------------------------
__device__ __forceinline__ void xcd_remap(int& bx, int& by, int& bz) {
  const int gx = gridDim.x, gy = gridDim.y;
  int lin = (blockIdx.z * gy + blockIdx.y) * gx + blockIdx.x;
  const int nwg = gx * gy * (int)gridDim.z;
  lin = (lin & 7) * (nwg >> 3) + (lin >> 3);
  bx = lin % gx;
  const int rem = lin / gx;
  by = rem % gy;
  bz = rem / gy;
}

// ---------------------------------------------------------------------------
// 128x128 m97-structure GEMM body. EPI: 0 = fp32 store, 1 = bf16 store,
// 2 = bf16 store transposed into vpT[b][d][n] (V-projection).
// KBOUND: K-loop bounded by n0+128 (PV: P[i][j]=0 for j>i).
// ---------------------------------------------------------------------------
template <int EPI, bool BIAS, bool KBOUND>
__device__ __forceinline__ void gemm_body(const bf16_t* __restrict__ A,
                                          const bf16_t* __restrict__ B,
                                          const float* __restrict__ bias,
                                          void* __restrict__ Cout,
                                          int N, int K, float alpha,
                                          int m0, int n0) {
  int KT = K >> 5;
  if (KBOUND) {
    int kb = (n0 + 128) >> 5;
    if (kb < KT) KT = kb;
  }

  __shared__ __align__(16) bf16_t As[128 * 32];
  __shared__ __align__(16) bf16_t Bs[128 * 32];

  const int t = threadIdx.x;
  const int l = t & 63;
  const int w = t >> 6;
  const int wr = w >> 1, wc = w & 1;

  const int c0 = t, c1 = t + 256;
  const bf16_t* a_src0 = A + (long)(m0 + (c0 >> 2)) * K + ((c0 & 3) << 3);
  const bf16_t* a_src1 = A + (long)(m0 + (c1 >> 2)) * K + ((c1 & 3) << 3);
  const bf16_t* b_src0 = B + (long)(n0 + (c0 >> 2)) * K + ((c0 & 3) << 3);
  const bf16_t* b_src1 = B + (long)(n0 + (c1 >> 2)) * K + ((c1 & 3) << 3);
  char* const asb = (char*)As;
  char* const bsb = (char*)Bs;
  char* const a_dst0 = asb + w * 1024;
  char* const a_dst1 = asb + 4096 + w * 1024;
  char* const b_dst0 = bsb + w * 1024;
  char* const b_dst1 = bsb + 4096 + w * 1024;

  const int r16 = l & 15, kg = l >> 4;
  int aoff[4], boff[4];
#pragma unroll
  for (int mi = 0; mi < 4; ++mi) aoff[mi] = (((wr * 64 + mi * 16 + r16) * 32) + kg * 8) * 2;
#pragma unroll
  for (int ni = 0; ni < 4; ++ni) boff[ni] = (((wc * 64 + ni * 16 + r16) * 32) + kg * 8) * 2;

  f32x4 acc[4][4] = {};

  for (int kt = 0; kt < KT; ++kt) {
    __syncthreads();
    GLD_LDS16(a_src0, a_dst0);
    GLD_LDS16(a_src1, a_dst1);
    GLD_LDS16(b_src0, b_dst0);
    GLD_LDS16(b_src1, b_dst1);
    a_src0 += 32; a_src1 += 32; b_src0 += 32; b_src1 += 32;
    __syncthreads();

    bf16x8 af[4], bfr[4];
#pragma unroll
    for (int mi = 0; mi < 4; ++mi) af[mi] = *(const bf16x8*)(asb + aoff[mi]);
#pragma unroll
    for (int ni = 0; ni < 4; ++ni) bfr[ni] = *(const bf16x8*)(bsb + boff[ni]);
#pragma unroll
    for (int mi = 0; mi < 4; ++mi)
#pragma unroll
      for (int ni = 0; ni < 4; ++ni)
        acc[mi][ni] = __builtin_amdgcn_mfma_f32_16x16x32_bf16(af[mi], bfr[ni], acc[mi][ni], 0, 0, 0);
  }

  const int rowbase = m0 + wr * 64 + ((l >> 4) << 2);
  const int colbase = n0 + wc * 64 + (l & 15);
  if constexpr (EPI == 0) {
    float* C = (float*)Cout;
#pragma unroll
    for (int mi = 0; mi < 4; ++mi)
#pragma unroll
      for (int ni = 0; ni < 4; ++ni) {
        const int col = colbase + ni * 16;
        float badd = 0.f;
        if constexpr (BIAS) badd = bias[col];
#pragma unroll
        for (int j = 0; j < 4; ++j)
          C[(long)(rowbase + mi * 16 + j) * N + col] = acc[mi][ni][j] * alpha + badd;
      }
  } else if constexpr (EPI == 1) {
    bf16_t* C = (bf16_t*)Cout;
#pragma unroll
    for (int mi = 0; mi < 4; ++mi)
#pragma unroll
      for (int ni = 0; ni < 4; ++ni) {
        const int col = colbase + ni * 16;
        float badd = 0.f;
        if constexpr (BIAS) badd = bias[col];
#pragma unroll
        for (int j = 0; j < 4; ++j)
          C[(long)(rowbase + mi * 16 + j) * N + col] = (bf16_t)(acc[mi][ni][j] * alpha + badd);
      }
  } else {
    bf16_t* C = (bf16_t*)Cout;  // vpT: per-batch [1024][2048]
#pragma unroll
    for (int mi = 0; mi < 4; ++mi)
#pragma unroll
      for (int ni = 0; ni < 4; ++ni) {
        const int col = colbase + ni * 16;
        float badd = 0.f;
        if constexpr (BIAS) badd = bias[col];
        const int row0 = rowbase + mi * 16;
        const int batch = row0 >> 11, nr = row0 & 2047;
        bf16x4 o;
#pragma unroll
        for (int j = 0; j < 4; ++j) o[j] = (bf16_t)(acc[mi][ni][j] + badd);
        *(bf16x4*)(C + (long)batch * (2048 * 1024) + (long)col * 2048 + nr) = o;
      }
  }
}

// z = batch index with element strides (PV / out-proj)
template <int EPI, bool BIAS, bool KBOUND>
__global__ __launch_bounds__(256, 4) void gemm_bt(const bf16_t* __restrict__ Ag,
                                                  const bf16_t* __restrict__ Bg,
                                                  const float* __restrict__ bias,
                                                  void* __restrict__ Cout,
                                                  int N, int K, float alpha,
                                                  long sAb, long sBb, long sCb, int eltC) {
  int bx, by, bz;
  xcd_remap(bx, by, bz);
  const int m0 = by << 7, n0 = bx << 7;
  gemm_body<EPI, BIAS, KBOUND>(Ag + (long)bz * sAb, Bg + (long)bz * sBb, bias,
                               (char*)Cout + (long)bz * sCb * eltC, N, K, alpha, m0, n0);
}

// ---------------------------------------------------------------------------
// Q,K projections fused: grid (8, 64, 2) = 1024 blocks (= 4/CU capacity).
// ---------------------------------------------------------------------------
struct QkArgs {
  const bf16_t* A[2];
  const bf16_t* W[2];
  const float* bias[2];
  bf16_t* C[2];
};

__global__ __launch_bounds__(256, 4) void gemm_qk(QkArgs a, int N, int K) {
  int bx, by, bz;
  xcd_remap(bx, by, bz);
  gemm_body<1, true, false>(a.A[bz], a.W[bz], a.bias[bz], a.C[bz], N, K, 1.0f,
                            by << 7, bx << 7);
}

// ---------------------------------------------------------------------------
// Fused scores + V-projection in ONE dispatch (grid packing: scores alone is
// 544 active blocks = 2.1/CU; adding V-proj's 512 blocks fills the machine).
// z<4: scores batch z (tile bx,by; causal skip; alpha=1/32).
// z>=4: V-proj tile lin=(z-4)*256+by*16+bx in (64 m-tiles x 8 n-tiles).
// ---------------------------------------------------------------------------
struct FsvArgs {
  const bf16_t* qp;
  const bf16_t* kp;
  bf16_t* S;        // [4][2048][2048]
  const bf16_t* vB; // [8192][1024]
  const bf16_t* Wv; // [1024][1024]
  const float* bv;
  bf16_t* vpT;      // [4][1024][2048]
  long nd, nn;
};

__global__ __launch_bounds__(256, 4) void fused_sv(FsvArgs a) {
  int bx, by, bz;
  xcd_remap(bx, by, bz);  // grid (16,16,6) = 1536 blocks
  if (bz < 4) {
    const int m0 = by << 7, n0 = bx << 7;
    if (n0 > m0 + 127) return;
    gemm_body<1, false, false>(a.qp + (long)bz * a.nd, a.kp + (long)bz * a.nd, nullptr,
                               a.S + (long)bz * a.nn, 2048, 1024, 0.03125f, m0, n0);
  } else {
    const int lin = (bz - 4) * 256 + by * 16 + bx;  // 0..511
    const int m0 = (lin >> 3) << 7, n0 = (lin & 7) << 7;
    gemm_body<2, true, false>(a.vB, a.Wv, a.bv, a.vpT, 1024, 1024, 1.0f, m0, n0);
  }
}

// ---------------------------------------------------------------------------
extern "C" void kernel_launch(void* const* d_in, const int* in_sizes, int n_in,
                              void* d_out, int out_size, void* d_ws, size_t ws_size,
                              hipStream_t stream) {
  const int b = 4, n = 2048, d = 1024;
  const long nd  = (long)n * d;
  const long bn  = (long)b * n;
  const long bnd = bn * d;
  const long ddl = (long)d * d;
  const long nn  = (long)n * n;

  const float* q  = (const float*)d_in[0];
  const float* k  = (const float*)d_in[1];
  const float* v  = (const float*)d_in[2];
  const float* Wq = (const float*)d_in[3];
  const float* bq = (const float*)d_in[4];
  const float* Wk = (const float*)d_in[5];
  const float* bk = (const float*)d_in[6];
  const float* Wv = (const float*)d_in[7];
  const float* bv = (const float*)d_in[8];
  const float* Wo = (const float*)d_in[9];
  const float* bo = (const float*)d_in[10];

  bf16_t* ws  = (bf16_t*)d_ws;
  bf16_t* qB  = ws;              // bnd
  bf16_t* kB  = qB + bnd;        // bnd
  bf16_t* vB  = kB + bnd;        // bnd
  bf16_t* WqB = vB + bnd;        // ddl x4
  bf16_t* WkB = WqB + ddl;
  bf16_t* WvB = WkB + ddl;
  bf16_t* WoB = WvB + ddl;
  bf16_t* qpB = WoB + ddl;       // bnd
  bf16_t* kpB = qpB + bnd;       // bnd
  bf16_t* vpT = kpB + bnd;       // bnd (per-batch [d][n], from fused_sv)
  bf16_t* S   = vpT + bnd;       // b*nn
  bf16_t* yT  = S + (long)b * nn;// bnd
  const size_t need = (size_t)(7 * bnd + 4 * ddl + (long)b * nn) * 2;
  if (ws_size < need) return;

  dim3 blk(256);

  // fp32 -> bf16 converts: ONE launch, 7 segments
  CvtArgs ca;
  ca.src[0] = q;  ca.dst[0] = qB;  ca.n4[0] = bnd / 4;
  ca.src[1] = k;  ca.dst[1] = kB;  ca.n4[1] = bnd / 4;
  ca.src[2] = v;  ca.dst[2] = vB;  ca.n4[2] = bnd / 4;
  ca.src[3] = Wq; ca.dst[3] = WqB; ca.n4[3] = ddl / 4;
  ca.src[4] = Wk; ca.dst[4] = WkB; ca.n4[4] = ddl / 4;
  ca.src[5] = Wv; ca.dst[5] = WvB; ca.n4[5] = ddl / 4;
  ca.src[6] = Wo; ca.dst[6] = WoB; ca.n4[6] = ddl / 4;
  cvt_all<<<dim3(512, 7), blk, 0, stream>>>(ca);

  // Q,K projections: grid (8, 64, 2) = 1024 blocks
  QkArgs qa;
  qa.A[0] = qB; qa.W[0] = WqB; qa.bias[0] = bq; qa.C[0] = qpB;
  qa.A[1] = kB; qa.W[1] = WkB; qa.bias[1] = bk; qa.C[1] = kpB;
  gemm_qk<<<dim3(d / 128, bn / 128, 2), blk, 0, stream>>>(qa, d, d);

  // fused scores (causal) + V-projection: grid (16,16,6) = 1536 blocks
  FsvArgs fa;
  fa.qp = qpB; fa.kp = kpB; fa.S = S;
  fa.vB = vB; fa.Wv = WvB; fa.bv = bv; fa.vpT = vpT;
  fa.nd = nd; fa.nn = nn;
  fused_sv<<<dim3(16, 16, 6), blk, 0, stream>>>(fa);

  // causal softmax in place (bounded to the straddle tile)
  softmax_causal<<<dim3(n, b), blk, 0, stream>>>(S, n, nn);

  // yT[z] = vpT[z] x P[z]^T   (K bounded per N-tile by causality)
  gemm_bt<1, false, true><<<dim3(n / 128, d / 128, b), blk, 0, stream>>>(
      vpT, S, nullptr, yT, n, n, 1.f, nd, nn, nd, 2);

  // out = y2 x Wo^T + bo ; y2 flat == yT flat, fp32 out
  gemm_bt<0, true, false><<<dim3(d / 128, bn / 128, 1), blk, 0, stream>>>(
      yT, WoB, bo, (float*)d_out, d, d, 1.f, 0, 0, 0, 4);
}

// Round 9
// 212.942 us; speedup vs baseline: 1.0259x; 1.0259x over previous
//
#include <hip/hip_runtime.h>
#include <hip/hip_bf16.h>
#include <stdint.h>

typedef __bf16 bf16_t;
typedef __bf16 bf16x8 __attribute__((ext_vector_type(8)));
typedef __bf16 bf16x4 __attribute__((ext_vector_type(4)));
typedef float f32x4 __attribute__((ext_vector_type(4)));

#define GLD_LDS16(src, dst)                                                              \
  __builtin_amdgcn_global_load_lds((const __attribute__((address_space(1))) void*)(src), \
                                   (__attribute__((address_space(3))) void*)(dst), 16, 0, 0)

#define BAR() __builtin_amdgcn_s_barrier()
#define LGKM0() asm volatile("s_waitcnt lgkmcnt(0)" ::: "memory")
#define VMCN(n) asm volatile("s_waitcnt vmcnt(" #n ")" ::: "memory")
#define SCH0() __builtin_amdgcn_sched_barrier(0)

__device__ __forceinline__ int swz(int x) { return x ^ (((x >> 9) & 1) << 5); }

// ---------------------------------------------------------------------------
// fp32 -> bf16 convert, ALL tensors in one launch. blockIdx.y = segment.
// ---------------------------------------------------------------------------
struct CvtArgs {
  const float* src[7];
  bf16_t* dst[7];
  long n4[7];
};

__global__ __launch_bounds__(256) void cvt_all(CvtArgs a) {
  const int seg = blockIdx.y;
  const float* __restrict__ in = a.src[seg];
  bf16_t* __restrict__ out = a.dst[seg];
  const long n4 = a.n4[seg];
  long i = (long)blockIdx.x * blockDim.x + threadIdx.x;
  const long stride = (long)gridDim.x * blockDim.x;
  for (; i < n4; i += stride) {
    float4 v = ((const float4*)in)[i];
    bf16x4 o;
    o[0] = (bf16_t)v.x; o[1] = (bf16_t)v.y; o[2] = (bf16_t)v.z; o[3] = (bf16_t)v.w;
    ((bf16x4*)out)[i] = o;
  }
}

// ---------------------------------------------------------------------------
// Causal row softmax, in-place, bounded: row i only touches
// j < jmax = (floor(i/128)+1)*128 (PV's KBOUND never reads past jmax).
// ---------------------------------------------------------------------------
__global__ __launch_bounds__(256) void softmax_causal(bf16_t* __restrict__ S, int n, long sB) {
  const int i = blockIdx.x;
  const int z = blockIdx.y;
  bf16_t* row = S + (long)z * sB + (long)i * n;
  const int t = threadIdx.x;
  const int j0 = t << 3;
  const int jmax = ((i >> 7) + 1) << 7;
  const bool active = j0 < jmax;

  float vals[8];
  float mx = -3.0e38f;
  if (active) {
    bf16x8 vv = ((const bf16x8*)row)[t];
#pragma unroll
    for (int e = 0; e < 8; ++e) {
      float v = (j0 + e <= i) ? (float)vv[e] : -3.0e38f;
      vals[e] = v;
      mx = fmaxf(mx, v);
    }
  }
#pragma unroll
  for (int off = 32; off; off >>= 1) mx = fmaxf(mx, __shfl_xor(mx, off));
  __shared__ float redm[4];
  if ((t & 63) == 0) redm[t >> 6] = mx;
  __syncthreads();
  mx = fmaxf(fmaxf(redm[0], redm[1]), fmaxf(redm[2], redm[3]));

  float sum = 0.f;
  if (active) {
#pragma unroll
    for (int e = 0; e < 8; ++e) {
      float p = (j0 + e <= i) ? __expf(vals[e] - mx) : 0.f;
      vals[e] = p;
      sum += p;
    }
  }
#pragma unroll
  for (int off = 32; off; off >>= 1) sum += __shfl_xor(sum, off);
  __shared__ float reds[4];
  if ((t & 63) == 0) reds[t >> 6] = sum;
  __syncthreads();
  sum = reds[0] + reds[1] + reds[2] + reds[3];
  const float inv = 1.0f / sum;

  if (active) {
    bf16x8 o;
#pragma unroll
    for (int e = 0; e < 8; ++e) o[e] = (bf16_t)(vals[e] * inv);
    ((bf16x8*)row)[t] = o;
  }
}

// ---------------------------------------------------------------------------
// XCD-chunked bijective remap (requires nwg % 8 == 0; all grids comply).
// ---------------------------------------------------------------------------
__device__ __forceinline__ void xcd_remap(int& bx, int& by, int& bz) {
  const int gx = gridDim.x, gy = gridDim.y;
  int lin = (blockIdx.z * gy + blockIdx.y) * gx + blockIdx.x;
  const int nwg = gx * gy * (int)gridDim.z;
  lin = (lin & 7) * (nwg >> 3) + (lin >> 3);
  bx = lin % gx;
  const int rem = lin / gx;
  by = rem % gy;
  bz = rem / gy;
}

// ---------------------------------------------------------------------------
// 128x128 m97-structure GEMM body. EPI: 0 = fp32 store, 1 = bf16 store.
// KBOUND: K-loop bounded by n0+128 (PV: P[i][j]=0 for j>i).
// ---------------------------------------------------------------------------
template <int EPI, bool BIAS, bool KBOUND>
__device__ __forceinline__ void gemm_body(const bf16_t* __restrict__ A,
                                          const bf16_t* __restrict__ B,
                                          const float* __restrict__ bias,
                                          void* __restrict__ Cout,
                                          int N, int K, float alpha,
                                          int m0, int n0) {
  int KT = K >> 5;
  if (KBOUND) {
    int kb = (n0 + 128) >> 5;
    if (kb < KT) KT = kb;
  }

  __shared__ __align__(16) bf16_t As[128 * 32];
  __shared__ __align__(16) bf16_t Bs[128 * 32];

  const int t = threadIdx.x;
  const int l = t & 63;
  const int w = t >> 6;
  const int wr = w >> 1, wc = w & 1;

  const int c0 = t, c1 = t + 256;
  const bf16_t* a_src0 = A + (long)(m0 + (c0 >> 2)) * K + ((c0 & 3) << 3);
  const bf16_t* a_src1 = A + (long)(m0 + (c1 >> 2)) * K + ((c1 & 3) << 3);
  const bf16_t* b_src0 = B + (long)(n0 + (c0 >> 2)) * K + ((c0 & 3) << 3);
  const bf16_t* b_src1 = B + (long)(n0 + (c1 >> 2)) * K + ((c1 & 3) << 3);
  char* const asb = (char*)As;
  char* const bsb = (char*)Bs;
  char* const a_dst0 = asb + w * 1024;
  char* const a_dst1 = asb + 4096 + w * 1024;
  char* const b_dst0 = bsb + w * 1024;
  char* const b_dst1 = bsb + 4096 + w * 1024;

  const int r16 = l & 15, kg = l >> 4;
  int aoff[4], boff[4];
#pragma unroll
  for (int mi = 0; mi < 4; ++mi) aoff[mi] = (((wr * 64 + mi * 16 + r16) * 32) + kg * 8) * 2;
#pragma unroll
  for (int ni = 0; ni < 4; ++ni) boff[ni] = (((wc * 64 + ni * 16 + r16) * 32) + kg * 8) * 2;

  f32x4 acc[4][4] = {};

  for (int kt = 0; kt < KT; ++kt) {
    __syncthreads();
    GLD_LDS16(a_src0, a_dst0);
    GLD_LDS16(a_src1, a_dst1);
    GLD_LDS16(b_src0, b_dst0);
    GLD_LDS16(b_src1, b_dst1);
    a_src0 += 32; a_src1 += 32; b_src0 += 32; b_src1 += 32;
    __syncthreads();

    bf16x8 af[4], bfr[4];
#pragma unroll
    for (int mi = 0; mi < 4; ++mi) af[mi] = *(const bf16x8*)(asb + aoff[mi]);
#pragma unroll
    for (int ni = 0; ni < 4; ++ni) bfr[ni] = *(const bf16x8*)(bsb + boff[ni]);
#pragma unroll
    for (int mi = 0; mi < 4; ++mi)
#pragma unroll
      for (int ni = 0; ni < 4; ++ni)
        acc[mi][ni] = __builtin_amdgcn_mfma_f32_16x16x32_bf16(af[mi], bfr[ni], acc[mi][ni], 0, 0, 0);
  }

  const int rowbase = m0 + wr * 64 + ((l >> 4) << 2);
  const int colbase = n0 + wc * 64 + (l & 15);
  if constexpr (EPI == 0) {
    float* C = (float*)Cout;
#pragma unroll
    for (int mi = 0; mi < 4; ++mi)
#pragma unroll
      for (int ni = 0; ni < 4; ++ni) {
        const int col = colbase + ni * 16;
        float badd = 0.f;
        if constexpr (BIAS) badd = bias[col];
#pragma unroll
        for (int j = 0; j < 4; ++j)
          C[(long)(rowbase + mi * 16 + j) * N + col] = acc[mi][ni][j] * alpha + badd;
      }
  } else {
    bf16_t* C = (bf16_t*)Cout;
#pragma unroll
    for (int mi = 0; mi < 4; ++mi)
#pragma unroll
      for (int ni = 0; ni < 4; ++ni) {
        const int col = colbase + ni * 16;
        float badd = 0.f;
        if constexpr (BIAS) badd = bias[col];
#pragma unroll
        for (int j = 0; j < 4; ++j)
          C[(long)(rowbase + mi * 16 + j) * N + col] = (bf16_t)(acc[mi][ni][j] * alpha + badd);
      }
  }
}

// z = batch index with element strides (PV / out-proj)
template <int EPI, bool BIAS, bool KBOUND>
__global__ __launch_bounds__(256, 4) void gemm_bt(const bf16_t* __restrict__ Ag,
                                                  const bf16_t* __restrict__ Bg,
                                                  const float* __restrict__ bias,
                                                  void* __restrict__ Cout,
                                                  int N, int K, float alpha,
                                                  long sAb, long sBb, long sCb, int eltC) {
  int bx, by, bz;
  xcd_remap(bx, by, bz);
  const int m0 = by << 7, n0 = bx << 7;
  gemm_body<EPI, BIAS, KBOUND>(Ag + (long)bz * sAb, Bg + (long)bz * sBb, bias,
                               (char*)Cout + (long)bz * sCb * eltC, N, K, alpha, m0, n0);
}

// ---------------------------------------------------------------------------
// Fused QKV projections (bf16 inputs), m97 structure, ONE body instance with
// a runtime epilogue branch (keeps LDS at 16 KB — the fused_sv lesson).
// z<2: qp/kp normal [8192,1024] store. z==2: V writes transposed vpT[b][d][n].
// ---------------------------------------------------------------------------
struct Qkv3Args {
  const bf16_t* A[3];
  const bf16_t* W[3];
  const float* bias[3];
  bf16_t* C[3];
};

__global__ __launch_bounds__(256, 4) void qkv3(Qkv3Args ga, int N, int K) {
  int bx, by, bz;
  xcd_remap(bx, by, bz);
  const int m0 = by << 7, n0 = bx << 7;

  const bf16_t* __restrict__ A = ga.A[bz];
  const bf16_t* __restrict__ B = ga.W[bz];
  const float* __restrict__ bias = ga.bias[bz];
  const int KT = K >> 5;

  __shared__ __align__(16) bf16_t As[128 * 32];
  __shared__ __align__(16) bf16_t Bs[128 * 32];

  const int t = threadIdx.x;
  const int l = t & 63;
  const int w = t >> 6;
  const int wr = w >> 1, wc = w & 1;

  const int c0 = t, c1 = t + 256;
  const bf16_t* a_src0 = A + (long)(m0 + (c0 >> 2)) * K + ((c0 & 3) << 3);
  const bf16_t* a_src1 = A + (long)(m0 + (c1 >> 2)) * K + ((c1 & 3) << 3);
  const bf16_t* b_src0 = B + (long)(n0 + (c0 >> 2)) * K + ((c0 & 3) << 3);
  const bf16_t* b_src1 = B + (long)(n0 + (c1 >> 2)) * K + ((c1 & 3) << 3);
  char* const asb = (char*)As;
  char* const bsb = (char*)Bs;
  char* const a_dst0 = asb + w * 1024;
  char* const a_dst1 = asb + 4096 + w * 1024;
  char* const b_dst0 = bsb + w * 1024;
  char* const b_dst1 = bsb + 4096 + w * 1024;

  const int r16 = l & 15, kg = l >> 4;
  int aoff[4], boff[4];
#pragma unroll
  for (int mi = 0; mi < 4; ++mi) aoff[mi] = (((wr * 64 + mi * 16 + r16) * 32) + kg * 8) * 2;
#pragma unroll
  for (int ni = 0; ni < 4; ++ni) boff[ni] = (((wc * 64 + ni * 16 + r16) * 32) + kg * 8) * 2;

  f32x4 acc[4][4] = {};

  for (int kt = 0; kt < KT; ++kt) {
    __syncthreads();
    GLD_LDS16(a_src0, a_dst0);
    GLD_LDS16(a_src1, a_dst1);
    GLD_LDS16(b_src0, b_dst0);
    GLD_LDS16(b_src1, b_dst1);
    a_src0 += 32; a_src1 += 32; b_src0 += 32; b_src1 += 32;
    __syncthreads();

    bf16x8 af[4], bfr[4];
#pragma unroll
    for (int mi = 0; mi < 4; ++mi) af[mi] = *(const bf16x8*)(asb + aoff[mi]);
#pragma unroll
    for (int ni = 0; ni < 4; ++ni) bfr[ni] = *(const bf16x8*)(bsb + boff[ni]);
#pragma unroll
    for (int mi = 0; mi < 4; ++mi)
#pragma unroll
      for (int ni = 0; ni < 4; ++ni)
        acc[mi][ni] = __builtin_amdgcn_mfma_f32_16x16x32_bf16(af[mi], bfr[ni], acc[mi][ni], 0, 0, 0);
  }

  const int rowbase = m0 + wr * 64 + ((l >> 4) << 2);
  const int colbase = n0 + wc * 64 + (l & 15);
  if (bz < 2) {
    bf16_t* C = ga.C[bz];  // [8192,1024]
#pragma unroll
    for (int mi = 0; mi < 4; ++mi)
#pragma unroll
      for (int ni = 0; ni < 4; ++ni) {
        const int col = colbase + ni * 16;
        const float badd = bias[col];
#pragma unroll
        for (int j = 0; j < 4; ++j)
          C[(long)(rowbase + mi * 16 + j) * N + col] = (bf16_t)(acc[mi][ni][j] + badd);
      }
  } else {
    bf16_t* C = ga.C[2];  // vpT: per-batch [1024][2048]
#pragma unroll
    for (int mi = 0; mi < 4; ++mi)
#pragma unroll
      for (int ni = 0; ni < 4; ++ni) {
        const int col = colbase + ni * 16;
        const float badd = bias[col];
        const int row0 = rowbase + mi * 16;
        const int batch = row0 >> 11, nr = row0 & 2047;
        bf16x4 o;
#pragma unroll
        for (int j = 0; j < 4; ++j) o[j] = (bf16_t)(acc[mi][ni][j] + badd);
        *(bf16x4*)(C + (long)batch * (2048 * 1024) + (long)col * 2048 + nr) = o;
      }
  }
}

// ===========================================================================
// 8-phase 256x256 GEMM, scores only (z = batch; alpha=1/32; causal tile skip).
// Verbatim from R5/R6 (single MODE instantiation).
// ===========================================================================
struct G8Args {
  const bf16_t* A;
  const bf16_t* B;
  bf16_t* C;
  long sA, sB, sC;
};

template <int HALF, int BUF>
__device__ __forceinline__ void stage8(char* lds, const bf16_t* srcH, const int (&soff)[2],
                                       int wid, int tile) {
  const bf16_t* s = srcH + tile * 64;
  char* d = lds + (HALF >= 2 ? 65536 : 0) + BUF * 32768 + (HALF & 1) * 16384 + wid * 2048;
  GLD_LDS16(s + soff[0], d);
  GLD_LDS16(s + soff[1], d + 1024);
}

template <int BUF, int QM>
__device__ __forceinline__ void rdA(char* lds, const int (&aoffp)[4][2], bf16x8 (&af)[4][2]) {
  char* b = lds + BUF * 32768 + QM * 16384;
#pragma unroll
  for (int mi = 0; mi < 4; ++mi)
#pragma unroll
    for (int kk = 0; kk < 2; ++kk) af[mi][kk] = *(const bf16x8*)(b + aoffp[mi][kk]);
}

template <int BUF, int QN>
__device__ __forceinline__ void rdB(char* lds, const int (&boffp)[2][2], bf16x8 (&bf)[2][2]) {
  char* b = lds + 65536 + BUF * 32768 + QN * 16384;
#pragma unroll
  for (int ni = 0; ni < 2; ++ni)
#pragma unroll
    for (int kk = 0; kk < 2; ++kk) bf[ni][kk] = *(const bf16x8*)(b + boffp[ni][kk]);
}

template <int QM, int QN>
__device__ __forceinline__ void mm16(f32x4 (&acc)[2][2][4][2], const bf16x8 (&af)[4][2],
                                     const bf16x8 (&bf)[2][2]) {
  __builtin_amdgcn_s_setprio(1);
#pragma unroll
  for (int mi = 0; mi < 4; ++mi)
#pragma unroll
    for (int ni = 0; ni < 2; ++ni)
#pragma unroll
      for (int kk = 0; kk < 2; ++kk)
        acc[QM][QN][mi][ni] = __builtin_amdgcn_mfma_f32_16x16x32_bf16(
            af[mi][kk], bf[ni][kk], acc[QM][QN][mi][ni], 0, 0, 0);
  __builtin_amdgcn_s_setprio(0);
}

template <bool LAST>
__device__ __forceinline__ void kiter(char* lds, int tt,
    const bf16_t* srcA0, const bf16_t* srcA1, const bf16_t* srcB0, const bf16_t* srcB1,
    const int (&soff)[2], int wid,
    const int (&aoffp)[4][2], const int (&boffp)[2][2],
    bf16x8 (&af)[4][2], bf16x8 (&bf0)[2][2], bf16x8 (&bf1)[2][2],
    f32x4 (&acc)[2][2][4][2]) {
  VMCN(8); LGKM0(); SCH0();
  mm16<0, 0>(acc, af, bf0);
  rdB<0, 1>(lds, boffp, bf1);
  stage8<1, 1>(lds, srcA1, soff, wid, tt + 1);
  SCH0(); BAR();
  VMCN(8); LGKM0(); SCH0();
  mm16<0, 1>(acc, af, bf1);
  rdA<0, 1>(lds, aoffp, af);
  if (!LAST) stage8<0, 0>(lds, srcA0, soff, wid, tt + 2);
  SCH0(); BAR();
  if (LAST) { VMCN(0); } else { VMCN(6); }
  LGKM0(); SCH0();
  mm16<1, 0>(acc, af, bf0);
  rdB<1, 0>(lds, boffp, bf0);
  if (!LAST) stage8<2, 0>(lds, srcB0, soff, wid, tt + 2);
  SCH0(); BAR();
  LGKM0(); SCH0();
  mm16<1, 1>(acc, af, bf1);
  rdA<1, 0>(lds, aoffp, af);
  if (!LAST) stage8<3, 0>(lds, srcB1, soff, wid, tt + 2);
  SCH0(); BAR();
  if (!LAST) { VMCN(8); }
  LGKM0(); SCH0();
  mm16<0, 0>(acc, af, bf0);
  rdB<1, 1>(lds, boffp, bf1);
  if (!LAST) stage8<1, 0>(lds, srcA1, soff, wid, tt + 2);
  SCH0(); BAR();
  if (!LAST) { VMCN(8); }
  LGKM0(); SCH0();
  mm16<0, 1>(acc, af, bf1);
  rdA<1, 1>(lds, aoffp, af);
  if (!LAST) stage8<0, 1>(lds, srcA0, soff, wid, tt + 3);
  SCH0(); BAR();
  if (!LAST) { VMCN(6); }
  LGKM0(); SCH0();
  mm16<1, 0>(acc, af, bf0);
  if (!LAST) rdB<0, 0>(lds, boffp, bf0);
  if (!LAST) stage8<2, 1>(lds, srcB0, soff, wid, tt + 3);
  SCH0(); BAR();
  LGKM0(); SCH0();
  mm16<1, 1>(acc, af, bf1);
  if (!LAST) rdA<0, 0>(lds, aoffp, af);
  if (!LAST) stage8<3, 1>(lds, srcB1, soff, wid, tt + 3);
  SCH0(); BAR();
}

__global__ __launch_bounds__(512, 2) void gemm8_scores(G8Args ga) {
  int bx, by, bz;
  xcd_remap(bx, by, bz);
  const int m0 = by << 8, n0 = bx << 8;
  if (n0 > m0 + 255) return;

  const int K = 1024, NT = 16;
  const bf16_t* A = ga.A + (long)bz * ga.sA;
  const bf16_t* B = ga.B + (long)bz * ga.sB;

  __shared__ __align__(16) char lds[131072];

  const int t = threadIdx.x;
  const int wid = t >> 6, l = t & 63;
  const int wm = wid >> 2, wn = wid & 3;
  const int ri16 = l & 15, kg = l >> 4;

  int soff[2];
#pragma unroll
  for (int i = 0; i < 2; ++i) {
    const int sub = wid * 2 + i;
    const int ri = l >> 2;
    const int cq = (l & 3) ^ ((ri & 8) >> 2);
    const int r = (sub >> 1) * 16 + ri;
    const int c = (sub & 1) * 32 + cq * 8;
    soff[i] = r * K + c;
  }
  const bf16_t* srcA0 = A + (long)m0 * K;
  const bf16_t* srcA1 = A + (long)(m0 + 128) * K;
  const bf16_t* srcB0 = B + (long)n0 * K;
  const bf16_t* srcB1 = B + (long)(n0 + 128) * K;

  int aoffp[4][2], boffp[2][2];
#pragma unroll
  for (int mi = 0; mi < 4; ++mi)
#pragma unroll
    for (int kk = 0; kk < 2; ++kk)
      aoffp[mi][kk] = swz((wm * 4 + mi) * 2048 + kk * 1024 + ri16 * 64 + kg * 16);
#pragma unroll
  for (int ni = 0; ni < 2; ++ni)
#pragma unroll
    for (int kk = 0; kk < 2; ++kk)
      boffp[ni][kk] = swz((wn * 2 + ni) * 2048 + kk * 1024 + ri16 * 64 + kg * 16);

  f32x4 acc[2][2][4][2] = {};
  bf16x8 af[4][2], bf0[2][2], bf1[2][2];

  stage8<0, 0>(lds, srcA0, soff, wid, 0);
  stage8<2, 0>(lds, srcB0, soff, wid, 0);
  stage8<3, 0>(lds, srcB1, soff, wid, 0);
  stage8<1, 0>(lds, srcA1, soff, wid, 0);
  stage8<0, 1>(lds, srcA0, soff, wid, 1);
  stage8<2, 1>(lds, srcB0, soff, wid, 1);
  stage8<3, 1>(lds, srcB1, soff, wid, 1);
  VMCN(6);
  BAR();
  rdA<0, 0>(lds, aoffp, af);
  rdB<0, 0>(lds, boffp, bf0);

  for (int tt = 0; tt + 2 < NT; tt += 2)
    kiter<false>(lds, tt, srcA0, srcA1, srcB0, srcB1, soff, wid, aoffp, boffp,
                 af, bf0, bf1, acc);
  kiter<true>(lds, NT - 2, srcA0, srcA1, srcB0, srcB1, soff, wid, aoffp, boffp,
              af, bf0, bf1, acc);

  bf16_t* C = ga.C + (long)bz * ga.sC;  // S[z]: [2048,2048]
#pragma unroll
  for (int qm = 0; qm < 2; ++qm)
#pragma unroll
    for (int qn = 0; qn < 2; ++qn)
#pragma unroll
      for (int mi = 0; mi < 4; ++mi)
#pragma unroll
        for (int ni = 0; ni < 2; ++ni) {
          const int col = n0 + qn * 128 + wn * 32 + ni * 16 + ri16;
          const int row0 = m0 + qm * 128 + wm * 64 + mi * 16 + kg * 4;
#pragma unroll
          for (int j = 0; j < 4; ++j)
            C[(long)(row0 + j) * 2048 + col] = (bf16_t)(acc[qm][qn][mi][ni][j] * 0.03125f);
        }
}

// ---------------------------------------------------------------------------
extern "C" void kernel_launch(void* const* d_in, const int* in_sizes, int n_in,
                              void* d_out, int out_size, void* d_ws, size_t ws_size,
                              hipStream_t stream) {
  const int b = 4, n = 2048, d = 1024;
  const long nd  = (long)n * d;
  const long bn  = (long)b * n;
  const long bnd = bn * d;
  const long ddl = (long)d * d;
  const long nn  = (long)n * n;

  const float* q  = (const float*)d_in[0];
  const float* k  = (const float*)d_in[1];
  const float* v  = (const float*)d_in[2];
  const float* Wq = (const float*)d_in[3];
  const float* bq = (const float*)d_in[4];
  const float* Wk = (const float*)d_in[5];
  const float* bk = (const float*)d_in[6];
  const float* Wv = (const float*)d_in[7];
  const float* bv = (const float*)d_in[8];
  const float* Wo = (const float*)d_in[9];
  const float* bo = (const float*)d_in[10];

  bf16_t* ws  = (bf16_t*)d_ws;
  bf16_t* qB  = ws;              // bnd
  bf16_t* kB  = qB + bnd;        // bnd
  bf16_t* vB  = kB + bnd;        // bnd
  bf16_t* WqB = vB + bnd;        // ddl x4
  bf16_t* WkB = WqB + ddl;
  bf16_t* WvB = WkB + ddl;
  bf16_t* WoB = WvB + ddl;
  bf16_t* qpB = WoB + ddl;       // bnd
  bf16_t* kpB = qpB + bnd;       // bnd
  bf16_t* vpT = kpB + bnd;       // bnd (per-batch [d][n], from qkv3 epilogue)
  bf16_t* S   = vpT + bnd;       // b*nn
  bf16_t* yT  = S + (long)b * nn;// bnd
  const size_t need = (size_t)(7 * bnd + 4 * ddl + (long)b * nn) * 2;
  if (ws_size < need) return;

  dim3 blk(256);

  // fp32 -> bf16 converts: ONE launch, 7 segments (HBM-bound, ~28 us)
  CvtArgs ca;
  ca.src[0] = q;  ca.dst[0] = qB;  ca.n4[0] = bnd / 4;
  ca.src[1] = k;  ca.dst[1] = kB;  ca.n4[1] = bnd / 4;
  ca.src[2] = v;  ca.dst[2] = vB;  ca.n4[2] = bnd / 4;
  ca.src[3] = Wq; ca.dst[3] = WqB; ca.n4[3] = ddl / 4;
  ca.src[4] = Wk; ca.dst[4] = WkB; ca.n4[4] = ddl / 4;
  ca.src[5] = Wv; ca.dst[5] = WvB; ca.n4[5] = ddl / 4;
  ca.src[6] = Wo; ca.dst[6] = WoB; ca.n4[6] = ddl / 4;
  cvt_all<<<dim3(512, 7), blk, 0, stream>>>(ca);

  // fused QKV projections (m97, single-body epilogue branch): (8,64,3)=1536
  Qkv3Args qa;
  qa.A[0] = qB; qa.W[0] = WqB; qa.bias[0] = bq; qa.C[0] = qpB;
  qa.A[1] = kB; qa.W[1] = WkB; qa.bias[1] = bk; qa.C[1] = kpB;
  qa.A[2] = vB; qa.W[2] = WvB; qa.bias[2] = bv; qa.C[2] = vpT;
  qkv3<<<dim3(d / 128, bn / 128, 3), blk, 0, stream>>>(qa, d, d);

  // scores: 8-phase 256^2, grid (8,8,4)=256 (144 active), ~26-30 us
  G8Args sa;
  sa.A = qpB; sa.B = kpB; sa.C = S;
  sa.sA = nd; sa.sB = nd; sa.sC = nn;
  gemm8_scores<<<dim3(n / 256, n / 256, b), dim3(512), 0, stream>>>(sa);

  // causal softmax in place (bounded to the straddle tile)
  softmax_causal<<<dim3(n, b), blk, 0, stream>>>(S, n, nn);

  // yT[z] = vpT[z] x P[z]^T   (K bounded per N-tile by causality)
  gemm_bt<1, false, true><<<dim3(n / 128, d / 128, b), blk, 0, stream>>>(
      vpT, S, nullptr, yT, n, n, 1.f, nd, nn, nd, 2);

  // out = y2 x Wo^T + bo ; y2 flat == yT flat, fp32 out
  gemm_bt<0, true, false><<<dim3(d / 128, bn / 128, 1), blk, 0, stream>>>(
      yT, WoB, bo, (float*)d_out, d, d, 1.f, 0, 0, 0, 4);
}

// Round 10
// 187.649 us; speedup vs baseline: 1.1642x; 1.1348x over previous
//
#include <hip/hip_runtime.h>
#include <hip/hip_bf16.h>
#include <stdint.h>

typedef __bf16 bf16_t;
typedef __bf16 bf16x8 __attribute__((ext_vector_type(8)));
typedef __bf16 bf16x4 __attribute__((ext_vector_type(4)));
typedef float f32x4 __attribute__((ext_vector_type(4)));

#define GLD_LDS16(src, dst)                                                              \
  __builtin_amdgcn_global_load_lds((const __attribute__((address_space(1))) void*)(src), \
                                   (__attribute__((address_space(3))) void*)(dst), 16, 0, 0)

// ---------------------------------------------------------------------------
// fp32 -> bf16 convert, ALL tensors in one launch. blockIdx.y = segment.
// ---------------------------------------------------------------------------
struct CvtArgs {
  const float* src[7];
  bf16_t* dst[7];
  long n4[7];
};

__global__ __launch_bounds__(256) void cvt_all(CvtArgs a) {
  const int seg = blockIdx.y;
  const float* __restrict__ in = a.src[seg];
  bf16_t* __restrict__ out = a.dst[seg];
  const long n4 = a.n4[seg];
  long i = (long)blockIdx.x * blockDim.x + threadIdx.x;
  const long stride = (long)gridDim.x * blockDim.x;
  for (; i < n4; i += stride) {
    float4 v = ((const float4*)in)[i];
    bf16x4 o;
    o[0] = (bf16_t)v.x; o[1] = (bf16_t)v.y; o[2] = (bf16_t)v.z; o[3] = (bf16_t)v.w;
    ((bf16x4*)out)[i] = o;
  }
}

// ---------------------------------------------------------------------------
// Causal row softmax, in-place, bounded: row i only touches
// j < jmax = (floor(i/128)+1)*128 (PV's KBOUND never reads past jmax).
// ---------------------------------------------------------------------------
__global__ __launch_bounds__(256) void softmax_causal(bf16_t* __restrict__ S, int n, long sB) {
  const int i = blockIdx.x;
  const int z = blockIdx.y;
  bf16_t* row = S + (long)z * sB + (long)i * n;
  const int t = threadIdx.x;
  const int j0 = t << 3;
  const int jmax = ((i >> 7) + 1) << 7;
  const bool active = j0 < jmax;

  float vals[8];
  float mx = -3.0e38f;
  if (active) {
    bf16x8 vv = ((const bf16x8*)row)[t];
#pragma unroll
    for (int e = 0; e < 8; ++e) {
      float v = (j0 + e <= i) ? (float)vv[e] : -3.0e38f;
      vals[e] = v;
      mx = fmaxf(mx, v);
    }
  }
#pragma unroll
  for (int off = 32; off; off >>= 1) mx = fmaxf(mx, __shfl_xor(mx, off));
  __shared__ float redm[4];
  if ((t & 63) == 0) redm[t >> 6] = mx;
  __syncthreads();
  mx = fmaxf(fmaxf(redm[0], redm[1]), fmaxf(redm[2], redm[3]));

  float sum = 0.f;
  if (active) {
#pragma unroll
    for (int e = 0; e < 8; ++e) {
      float p = (j0 + e <= i) ? __expf(vals[e] - mx) : 0.f;
      vals[e] = p;
      sum += p;
    }
  }
#pragma unroll
  for (int off = 32; off; off >>= 1) sum += __shfl_xor(sum, off);
  __shared__ float reds[4];
  if ((t & 63) == 0) reds[t >> 6] = sum;
  __syncthreads();
  sum = reds[0] + reds[1] + reds[2] + reds[3];
  const float inv = 1.0f / sum;

  if (active) {
    bf16x8 o;
#pragma unroll
    for (int e = 0; e < 8; ++e) o[e] = (bf16_t)(vals[e] * inv);
    ((bf16x8*)row)[t] = o;
  }
}

// ---------------------------------------------------------------------------
// XCD-chunked bijective remap (requires nwg % 8 == 0; all grids comply).
// ---------------------------------------------------------------------------
__device__ __forceinline__ void xcd_remap(int& bx, int& by, int& bz) {
  const int gx = gridDim.x, gy = gridDim.y;
  int lin = (blockIdx.z * gy + blockIdx.y) * gx + blockIdx.x;
  const int nwg = gx * gy * (int)gridDim.z;
  lin = (lin & 7) * (nwg >> 3) + (lin >> 3);
  bx = lin % gx;
  const int rem = lin / gx;
  by = rem % gy;
  bz = rem / gy;
}

// ---------------------------------------------------------------------------
// 128x128 GEMM core, BK=64, two inner k-passes (32 MFMA per barrier pair),
// XOR-swizzled LDS (T2, both-sides): stage slot (c&7)^(row&7) via pre-swizzled
// DMA source; read slot (kp*4+kg)^(row&7). Rows 0-7 hit 8 distinct 16B slots
// spanning all 32 banks -> 2 lanes/bank (free). acc returned to caller, which
// owns the epilogue; smem (32 KB) passed in so kernels allocate it ONCE.
// ---------------------------------------------------------------------------
__device__ __forceinline__ void gemm_core(char* smem,
                                          const bf16_t* __restrict__ A,
                                          const bf16_t* __restrict__ B,
                                          int K, int KT, int m0, int n0,
                                          f32x4 (&acc)[4][4]) {
  char* const asb = smem;
  char* const bsb = smem + 16384;
  const int t = threadIdx.x;
  const int l = t & 63;
  const int w = t >> 6;
  const int wr = w >> 1, wc = w & 1;
  const int r16 = l & 15, kg = l >> 4;

  // staging: 1024 16B chunks per tensor per K-tile; chunk c -> row c>>3,
  // phys slot c&7 holds logical slot (c&7)^(row&7)  (swizzle pre-applied).
  const bf16_t* a_src[4];
  const bf16_t* b_src[4];
#pragma unroll
  for (int i = 0; i < 4; ++i) {
    const int c = i * 256 + t;
    const int row = c >> 3;
    const int sl = (c & 7) ^ (row & 7);
    a_src[i] = A + (long)(m0 + row) * K + sl * 8;
    b_src[i] = B + (long)(n0 + row) * K + sl * 8;
  }

  // fragment read offsets: logical slot kp*4+kg at phys (kp*4+kg)^(row&7)
  int aoff[2][4], boff[2][4];
#pragma unroll
  for (int kp = 0; kp < 2; ++kp)
#pragma unroll
    for (int mi = 0; mi < 4; ++mi) {
      const int ra = wr * 64 + mi * 16 + r16;
      aoff[kp][mi] = ra * 128 + ((kp * 4 + kg) ^ (ra & 7)) * 16;
      const int rb = wc * 64 + mi * 16 + r16;
      boff[kp][mi] = rb * 128 + ((kp * 4 + kg) ^ (rb & 7)) * 16;
    }

  for (int kt = 0; kt < KT; ++kt) {
    __syncthreads();
#pragma unroll
    for (int i = 0; i < 4; ++i) {
      GLD_LDS16(a_src[i], asb + i * 4096 + w * 1024);
      GLD_LDS16(b_src[i], bsb + i * 4096 + w * 1024);
      a_src[i] += 64;
      b_src[i] += 64;
    }
    __syncthreads();

#pragma unroll
    for (int kp = 0; kp < 2; ++kp) {
      bf16x8 af[4], bfr[4];
#pragma unroll
      for (int mi = 0; mi < 4; ++mi) af[mi] = *(const bf16x8*)(asb + aoff[kp][mi]);
#pragma unroll
      for (int ni = 0; ni < 4; ++ni) bfr[ni] = *(const bf16x8*)(bsb + boff[kp][ni]);
#pragma unroll
      for (int mi = 0; mi < 4; ++mi)
#pragma unroll
        for (int ni = 0; ni < 4; ++ni)
          acc[mi][ni] =
              __builtin_amdgcn_mfma_f32_16x16x32_bf16(af[mi], bfr[ni], acc[mi][ni], 0, 0, 0);
    }
  }
}

// ---------------------------------------------------------------------------
// Generic GEMM kernel: C = alpha*A[M,K]*B[N,K]^T (+bias). EPI 0=fp32, 1=bf16.
// CAUSAL: skip tiles above diagonal (scores). KBOUND: K limited to n0+128 (PV).
// ---------------------------------------------------------------------------
template <int EPI, bool BIAS, bool CAUSAL, bool KBOUND>
__global__ __launch_bounds__(256, 3) void gemm_bt(const bf16_t* __restrict__ Ag,
                                                  const bf16_t* __restrict__ Bg,
                                                  const float* __restrict__ bias,
                                                  void* __restrict__ Cout,
                                                  int N, int K, float alpha,
                                                  long sAb, long sBb, long sCb, int eltC) {
  int bx, by, bz;
  xcd_remap(bx, by, bz);
  const int m0 = by << 7, n0 = bx << 7;
  if (CAUSAL && n0 > m0 + 127) return;

  int KT = K >> 6;
  if (KBOUND) {
    const int kb = (n0 + 128) >> 6;
    if (kb < KT) KT = kb;
  }

  __shared__ __align__(16) char smem[32768];
  f32x4 acc[4][4] = {};
  gemm_core(smem, Ag + (long)bz * sAb, Bg + (long)bz * sBb, K, KT, m0, n0, acc);

  const int t = threadIdx.x;
  const int l = t & 63;
  const int w = t >> 6;
  const int wr = w >> 1, wc = w & 1;
  const int rowbase = m0 + wr * 64 + ((l >> 4) << 2);
  const int colbase = n0 + wc * 64 + (l & 15);
  if constexpr (EPI == 0) {
    float* C = (float*)((char*)Cout + (long)bz * sCb * eltC);
#pragma unroll
    for (int mi = 0; mi < 4; ++mi)
#pragma unroll
      for (int ni = 0; ni < 4; ++ni) {
        const int col = colbase + ni * 16;
        float badd = 0.f;
        if constexpr (BIAS) badd = bias[col];
#pragma unroll
        for (int j = 0; j < 4; ++j)
          C[(long)(rowbase + mi * 16 + j) * N + col] = acc[mi][ni][j] * alpha + badd;
      }
  } else {
    bf16_t* C = (bf16_t*)((char*)Cout + (long)bz * sCb * eltC);
#pragma unroll
    for (int mi = 0; mi < 4; ++mi)
#pragma unroll
      for (int ni = 0; ni < 4; ++ni) {
        const int col = colbase + ni * 16;
        float badd = 0.f;
        if constexpr (BIAS) badd = bias[col];
#pragma unroll
        for (int j = 0; j < 4; ++j)
          C[(long)(rowbase + mi * 16 + j) * N + col] = (bf16_t)(acc[mi][ni][j] * alpha + badd);
      }
  }
}

// ---------------------------------------------------------------------------
// Fused QKV projections. z<2: qp/kp normal store. z==2: V-projection output is
// transposed into vpT[b][d][n] via an LDS transpose (reusing the 32 KB smem)
// so global stores are coalesced 16B along n (fixes the 8B-scatter epilogue).
// ---------------------------------------------------------------------------
struct Qkv3Args {
  const bf16_t* A[3];
  const bf16_t* W[3];
  const float* bias[3];
  bf16_t* C[3];
};

__global__ __launch_bounds__(256, 3) void qkv3(Qkv3Args ga, int N, int K) {
  int bx, by, bz;
  xcd_remap(bx, by, bz);
  const int m0 = by << 7, n0 = bx << 7;

  __shared__ __align__(16) char smem[32768];
  f32x4 acc[4][4] = {};
  gemm_core(smem, ga.A[bz], ga.W[bz], K, K >> 6, m0, n0, acc);

  const float* __restrict__ bias = ga.bias[bz];
  const int t = threadIdx.x;
  const int l = t & 63;
  const int w = t >> 6;
  const int wr = w >> 1, wc = w & 1;
  const int r16 = l & 15, kg = l >> 4;

  if (bz < 2) {
    bf16_t* C = ga.C[bz];  // [8192,1024]
    const int rowbase = m0 + wr * 64 + kg * 4;
    const int colbase = n0 + wc * 64 + r16;
#pragma unroll
    for (int mi = 0; mi < 4; ++mi)
#pragma unroll
      for (int ni = 0; ni < 4; ++ni) {
        const int col = colbase + ni * 16;
        const float badd = bias[col];
#pragma unroll
        for (int j = 0; j < 4; ++j)
          C[(long)(rowbase + mi * 16 + j) * N + col] = (bf16_t)(acc[mi][ni][j] + badd);
      }
  } else {
    // transpose in LDS: tt[local_col(d)][local_row(n)], then coalesced stores
    __syncthreads();  // K-loop LDS reads complete before overwrite
    bf16_t* tt = (bf16_t*)smem;  // [128][128]
#pragma unroll
    for (int mi = 0; mi < 4; ++mi)
#pragma unroll
      for (int ni = 0; ni < 4; ++ni) {
        const int lc = wc * 64 + ni * 16 + r16;
        const int lr = wr * 64 + mi * 16 + kg * 4;
        const float badd = bias[n0 + lc];
        bf16x4 o;
#pragma unroll
        for (int j = 0; j < 4; ++j) o[j] = (bf16_t)(acc[mi][ni][j] + badd);
        *(bf16x4*)(tt + lc * 128 + lr) = o;
      }
    __syncthreads();
    bf16_t* C = ga.C[2];  // vpT: per-batch [1024][2048]
    const int batch = m0 >> 11, nb = m0 & 2047;
#pragma unroll
    for (int i = 0; i < 8; ++i) {
      const int c = i * 256 + t;
      const int lc = c >> 4, ch = c & 15;
      *(bf16x8*)(C + (long)batch * (2048 * 1024) + (long)(n0 + lc) * 2048 + nb + ch * 8) =
          *(const bf16x8*)(tt + lc * 128 + ch * 8);
    }
  }
}

// ---------------------------------------------------------------------------
extern "C" void kernel_launch(void* const* d_in, const int* in_sizes, int n_in,
                              void* d_out, int out_size, void* d_ws, size_t ws_size,
                              hipStream_t stream) {
  const int b = 4, n = 2048, d = 1024;
  const long nd  = (long)n * d;
  const long bn  = (long)b * n;
  const long bnd = bn * d;
  const long ddl = (long)d * d;
  const long nn  = (long)n * n;

  const float* q  = (const float*)d_in[0];
  const float* k  = (const float*)d_in[1];
  const float* v  = (const float*)d_in[2];
  const float* Wq = (const float*)d_in[3];
  const float* bq = (const float*)d_in[4];
  const float* Wk = (const float*)d_in[5];
  const float* bk = (const float*)d_in[6];
  const float* Wv = (const float*)d_in[7];
  const float* bv = (const float*)d_in[8];
  const float* Wo = (const float*)d_in[9];
  const float* bo = (const float*)d_in[10];

  bf16_t* ws  = (bf16_t*)d_ws;
  bf16_t* qB  = ws;              // bnd
  bf16_t* kB  = qB + bnd;        // bnd
  bf16_t* vB  = kB + bnd;        // bnd
  bf16_t* WqB = vB + bnd;        // ddl x4
  bf16_t* WkB = WqB + ddl;
  bf16_t* WvB = WkB + ddl;
  bf16_t* WoB = WvB + ddl;
  bf16_t* qpB = WoB + ddl;       // bnd
  bf16_t* kpB = qpB + bnd;       // bnd
  bf16_t* vpT = kpB + bnd;       // bnd (per-batch [d][n], from qkv3 epilogue)
  bf16_t* S   = vpT + bnd;       // b*nn
  bf16_t* yT  = S + (long)b * nn;// bnd
  const size_t need = (size_t)(7 * bnd + 4 * ddl + (long)b * nn) * 2;
  if (ws_size < need) return;

  dim3 blk(256);

  // fp32 -> bf16 converts: ONE launch, 7 segments
  CvtArgs ca;
  ca.src[0] = q;  ca.dst[0] = qB;  ca.n4[0] = bnd / 4;
  ca.src[1] = k;  ca.dst[1] = kB;  ca.n4[1] = bnd / 4;
  ca.src[2] = v;  ca.dst[2] = vB;  ca.n4[2] = bnd / 4;
  ca.src[3] = Wq; ca.dst[3] = WqB; ca.n4[3] = ddl / 4;
  ca.src[4] = Wk; ca.dst[4] = WkB; ca.n4[4] = ddl / 4;
  ca.src[5] = Wv; ca.dst[5] = WvB; ca.n4[5] = ddl / 4;
  ca.src[6] = Wo; ca.dst[6] = WoB; ca.n4[6] = ddl / 4;
  cvt_all<<<dim3(512, 7), blk, 0, stream>>>(ca);

  // fused QKV projections (BK=64 core): grid (8, 64, 3) = 1536 blocks
  Qkv3Args qa;
  qa.A[0] = qB; qa.W[0] = WqB; qa.bias[0] = bq; qa.C[0] = qpB;
  qa.A[1] = kB; qa.W[1] = WkB; qa.bias[1] = bk; qa.C[1] = kpB;
  qa.A[2] = vB; qa.W[2] = WvB; qa.bias[2] = bv; qa.C[2] = vpT;
  qkv3<<<dim3(d / 128, bn / 128, 3), blk, 0, stream>>>(qa, d, d);

  // scores: S[z] = qp[z] x kp[z]^T * (1/32), causal tile-skip
  gemm_bt<1, false, true, false><<<dim3(n / 128, n / 128, b), blk, 0, stream>>>(
      qpB, kpB, nullptr, S, n, d, 0.03125f, nd, nd, nn, 2);

  // causal softmax in place (bounded to the straddle tile)
  softmax_causal<<<dim3(n, b), blk, 0, stream>>>(S, n, nn);

  // yT[z] = vpT[z] x P[z]^T   (K bounded per N-tile by causality)
  gemm_bt<1, false, false, true><<<dim3(n / 128, d / 128, b), blk, 0, stream>>>(
      vpT, S, nullptr, yT, n, n, 1.f, nd, nn, nd, 2);

  // out = y2 x Wo^T + bo ; y2 flat == yT flat, fp32 out
  gemm_bt<0, true, false, false><<<dim3(d / 128, bn / 128, 1), blk, 0, stream>>>(
      yT, WoB, bo, (float*)d_out, d, d, 1.f, 0, 0, 0, 4);
}

// Round 11
// 182.672 us; speedup vs baseline: 1.1959x; 1.0272x over previous
//
#include <hip/hip_runtime.h>
#include <hip/hip_bf16.h>
#include <stdint.h>

typedef __bf16 bf16_t;
typedef __bf16 bf16x8 __attribute__((ext_vector_type(8)));
typedef __bf16 bf16x4 __attribute__((ext_vector_type(4)));
typedef float f32x4 __attribute__((ext_vector_type(4)));

#define GLD_LDS16(src, dst)                                                              \
  __builtin_amdgcn_global_load_lds((const __attribute__((address_space(1))) void*)(src), \
                                   (__attribute__((address_space(3))) void*)(dst), 16, 0, 0)

// ---------------------------------------------------------------------------
// fp32 -> bf16 convert, ALL tensors in one launch. blockIdx.y = segment.
// ---------------------------------------------------------------------------
struct CvtArgs {
  const float* src[7];
  bf16_t* dst[7];
  long n4[7];
};

__global__ __launch_bounds__(256) void cvt_all(CvtArgs a) {
  const int seg = blockIdx.y;
  const float* __restrict__ in = a.src[seg];
  bf16_t* __restrict__ out = a.dst[seg];
  const long n4 = a.n4[seg];
  long i = (long)blockIdx.x * blockDim.x + threadIdx.x;
  const long stride = (long)gridDim.x * blockDim.x;
  for (; i < n4; i += stride) {
    float4 v = ((const float4*)in)[i];
    bf16x4 o;
    o[0] = (bf16_t)v.x; o[1] = (bf16_t)v.y; o[2] = (bf16_t)v.z; o[3] = (bf16_t)v.w;
    ((bf16x4*)out)[i] = o;
  }
}

// ---------------------------------------------------------------------------
// Causal row softmax, in-place, bounded: row i only touches
// j < jmax = (floor(i/128)+1)*128 (PV's KBOUND never reads past jmax).
// ---------------------------------------------------------------------------
__global__ __launch_bounds__(256) void softmax_causal(bf16_t* __restrict__ S, int n, long sB) {
  const int i = blockIdx.x;
  const int z = blockIdx.y;
  bf16_t* row = S + (long)z * sB + (long)i * n;
  const int t = threadIdx.x;
  const int j0 = t << 3;
  const int jmax = ((i >> 7) + 1) << 7;
  const bool active = j0 < jmax;

  float vals[8];
  float mx = -3.0e38f;
  if (active) {
    bf16x8 vv = ((const bf16x8*)row)[t];
#pragma unroll
    for (int e = 0; e < 8; ++e) {
      float v = (j0 + e <= i) ? (float)vv[e] : -3.0e38f;
      vals[e] = v;
      mx = fmaxf(mx, v);
    }
  }
#pragma unroll
  for (int off = 32; off; off >>= 1) mx = fmaxf(mx, __shfl_xor(mx, off));
  __shared__ float redm[4];
  if ((t & 63) == 0) redm[t >> 6] = mx;
  __syncthreads();
  mx = fmaxf(fmaxf(redm[0], redm[1]), fmaxf(redm[2], redm[3]));

  float sum = 0.f;
  if (active) {
#pragma unroll
    for (int e = 0; e < 8; ++e) {
      float p = (j0 + e <= i) ? __expf(vals[e] - mx) : 0.f;
      vals[e] = p;
      sum += p;
    }
  }
#pragma unroll
  for (int off = 32; off; off >>= 1) sum += __shfl_xor(sum, off);
  __shared__ float reds[4];
  if ((t & 63) == 0) reds[t >> 6] = sum;
  __syncthreads();
  sum = reds[0] + reds[1] + reds[2] + reds[3];
  const float inv = 1.0f / sum;

  if (active) {
    bf16x8 o;
#pragma unroll
    for (int e = 0; e < 8; ++e) o[e] = (bf16_t)(vals[e] * inv);
    ((bf16x8*)row)[t] = o;
  }
}

// ---------------------------------------------------------------------------
// XCD-chunked bijective remap (requires nwg % 8 == 0; all grids comply).
// ---------------------------------------------------------------------------
__device__ __forceinline__ void xcd_remap(int& bx, int& by, int& bz) {
  const int gx = gridDim.x, gy = gridDim.y;
  int lin = (blockIdx.z * gy + blockIdx.y) * gx + blockIdx.x;
  const int nwg = gx * gy * (int)gridDim.z;
  lin = (lin & 7) * (nwg >> 3) + (lin >> 3);
  bx = lin % gx;
  const int rem = lin / gx;
  by = rem % gy;
  bz = rem / gy;
}

// ---------------------------------------------------------------------------
// 128x128 GEMM core, BK=64, two inner k-passes (32 MFMA per barrier pair),
// XOR-swizzled LDS (T2, both-sides): stage slot (c&7)^(row&7) via pre-swizzled
// DMA source; read slot (kp*4+kg)^(row&7).
// ---------------------------------------------------------------------------
__device__ __forceinline__ void gemm_core(char* smem,
                                          const bf16_t* __restrict__ A,
                                          const bf16_t* __restrict__ B,
                                          int K, int KT, int m0, int n0,
                                          f32x4 (&acc)[4][4]) {
  char* const asb = smem;
  char* const bsb = smem + 16384;
  const int t = threadIdx.x;
  const int l = t & 63;
  const int w = t >> 6;
  const int wr = w >> 1, wc = w & 1;
  const int r16 = l & 15, kg = l >> 4;

  const bf16_t* a_src[4];
  const bf16_t* b_src[4];
#pragma unroll
  for (int i = 0; i < 4; ++i) {
    const int c = i * 256 + t;
    const int row = c >> 3;
    const int sl = (c & 7) ^ (row & 7);
    a_src[i] = A + (long)(m0 + row) * K + sl * 8;
    b_src[i] = B + (long)(n0 + row) * K + sl * 8;
  }

  int aoff[2][4], boff[2][4];
#pragma unroll
  for (int kp = 0; kp < 2; ++kp)
#pragma unroll
    for (int mi = 0; mi < 4; ++mi) {
      const int ra = wr * 64 + mi * 16 + r16;
      aoff[kp][mi] = ra * 128 + ((kp * 4 + kg) ^ (ra & 7)) * 16;
      const int rb = wc * 64 + mi * 16 + r16;
      boff[kp][mi] = rb * 128 + ((kp * 4 + kg) ^ (rb & 7)) * 16;
    }

  for (int kt = 0; kt < KT; ++kt) {
    __syncthreads();
#pragma unroll
    for (int i = 0; i < 4; ++i) {
      GLD_LDS16(a_src[i], asb + i * 4096 + w * 1024);
      GLD_LDS16(b_src[i], bsb + i * 4096 + w * 1024);
      a_src[i] += 64;
      b_src[i] += 64;
    }
    __syncthreads();

#pragma unroll
    for (int kp = 0; kp < 2; ++kp) {
      bf16x8 af[4], bfr[4];
#pragma unroll
      for (int mi = 0; mi < 4; ++mi) af[mi] = *(const bf16x8*)(asb + aoff[kp][mi]);
#pragma unroll
      for (int ni = 0; ni < 4; ++ni) bfr[ni] = *(const bf16x8*)(bsb + boff[kp][ni]);
#pragma unroll
      for (int mi = 0; mi < 4; ++mi)
#pragma unroll
        for (int ni = 0; ni < 4; ++ni)
          acc[mi][ni] =
              __builtin_amdgcn_mfma_f32_16x16x32_bf16(af[mi], bfr[ni], acc[mi][ni], 0, 0, 0);
    }
  }
}

// ---------------------------------------------------------------------------
// Generic GEMM kernel: C = alpha*A[M,K]*B[N,K]^T (+bias). EPI 0=fp32, 1=bf16.
// CAUSAL: skip tiles above diagonal (scores). KBOUND: K limited to n0+128 (PV).
// launch_bounds(256,4): 4 blocks/CU (LDS 4x32=128<=160 KB; 60 VGPR + 64 acc
// = 124 <= 128 regs at 4 waves/SIMD).
// ---------------------------------------------------------------------------
template <int EPI, bool BIAS, bool CAUSAL, bool KBOUND>
__global__ __launch_bounds__(256, 4) void gemm_bt(const bf16_t* __restrict__ Ag,
                                                  const bf16_t* __restrict__ Bg,
                                                  const float* __restrict__ bias,
                                                  void* __restrict__ Cout,
                                                  int N, int K, float alpha,
                                                  long sAb, long sBb, long sCb, int eltC) {
  int bx, by, bz;
  xcd_remap(bx, by, bz);
  const int m0 = by << 7, n0 = bx << 7;
  if (CAUSAL && n0 > m0 + 127) return;

  int KT = K >> 6;
  if (KBOUND) {
    const int kb = (n0 + 128) >> 6;
    if (kb < KT) KT = kb;
  }

  __shared__ __align__(16) char smem[32768];
  f32x4 acc[4][4] = {};
  gemm_core(smem, Ag + (long)bz * sAb, Bg + (long)bz * sBb, K, KT, m0, n0, acc);

  const int t = threadIdx.x;
  const int l = t & 63;
  const int w = t >> 6;
  const int wr = w >> 1, wc = w & 1;
  const int rowbase = m0 + wr * 64 + ((l >> 4) << 2);
  const int colbase = n0 + wc * 64 + (l & 15);
  if constexpr (EPI == 0) {
    float* C = (float*)((char*)Cout + (long)bz * sCb * eltC);
#pragma unroll
    for (int mi = 0; mi < 4; ++mi)
#pragma unroll
      for (int ni = 0; ni < 4; ++ni) {
        const int col = colbase + ni * 16;
        float badd = 0.f;
        if constexpr (BIAS) badd = bias[col];
#pragma unroll
        for (int j = 0; j < 4; ++j)
          C[(long)(rowbase + mi * 16 + j) * N + col] = acc[mi][ni][j] * alpha + badd;
      }
  } else {
    bf16_t* C = (bf16_t*)((char*)Cout + (long)bz * sCb * eltC);
#pragma unroll
    for (int mi = 0; mi < 4; ++mi)
#pragma unroll
      for (int ni = 0; ni < 4; ++ni) {
        const int col = colbase + ni * 16;
        float badd = 0.f;
        if constexpr (BIAS) badd = bias[col];
#pragma unroll
        for (int j = 0; j < 4; ++j)
          C[(long)(rowbase + mi * 16 + j) * N + col] = (bf16_t)(acc[mi][ni][j] * alpha + badd);
      }
  }
}

// ---------------------------------------------------------------------------
// Fused QKV projections. z<2: qp/kp normal store. z==2: V-projection output is
// transposed into vpT[b][d][n] via an LDS transpose (reusing the 32 KB smem).
// tt layout XOR-swizzled in 16B chunks (logical chunk ch of row lc lives at
// phys chunk ch^(lc&7)) so the column-major bf16x4 writes spread across banks
// instead of the 16-way conflict of the linear layout; reads stay 16B-slot
// disjoint (a permutation per row).
// ---------------------------------------------------------------------------
struct Qkv3Args {
  const bf16_t* A[3];
  const bf16_t* W[3];
  const float* bias[3];
  bf16_t* C[3];
};

__global__ __launch_bounds__(256, 4) void qkv3(Qkv3Args ga, int N, int K) {
  int bx, by, bz;
  xcd_remap(bx, by, bz);
  const int m0 = by << 7, n0 = bx << 7;

  __shared__ __align__(16) char smem[32768];
  f32x4 acc[4][4] = {};
  gemm_core(smem, ga.A[bz], ga.W[bz], K, K >> 6, m0, n0, acc);

  const float* __restrict__ bias = ga.bias[bz];
  const int t = threadIdx.x;
  const int l = t & 63;
  const int w = t >> 6;
  const int wr = w >> 1, wc = w & 1;
  const int r16 = l & 15, kg = l >> 4;

  if (bz < 2) {
    bf16_t* C = ga.C[bz];  // [8192,1024]
    const int rowbase = m0 + wr * 64 + kg * 4;
    const int colbase = n0 + wc * 64 + r16;
#pragma unroll
    for (int mi = 0; mi < 4; ++mi)
#pragma unroll
      for (int ni = 0; ni < 4; ++ni) {
        const int col = colbase + ni * 16;
        const float badd = bias[col];
#pragma unroll
        for (int j = 0; j < 4; ++j)
          C[(long)(rowbase + mi * 16 + j) * N + col] = (bf16_t)(acc[mi][ni][j] + badd);
      }
  } else {
    // transpose in LDS (chunk-XOR swizzled), then coalesced 16B stores along n
    __syncthreads();  // K-loop LDS reads complete before overwrite
    char* tt = smem;  // [128 rows(d)][256 B], phys chunk = logical^(lc&7)
#pragma unroll
    for (int mi = 0; mi < 4; ++mi)
#pragma unroll
      for (int ni = 0; ni < 4; ++ni) {
        const int lc = wc * 64 + ni * 16 + r16;       // local d-col
        const int lrb = (wr * 64 + mi * 16 + kg * 4) * 2;  // local n-row byte
        const float badd = bias[n0 + lc];
        bf16x4 o;
#pragma unroll
        for (int j = 0; j < 4; ++j) o[j] = (bf16_t)(acc[mi][ni][j] + badd);
        *(bf16x4*)(tt + lc * 256 + (lrb ^ ((lc & 7) << 4))) = o;
      }
    __syncthreads();
    bf16_t* C = ga.C[2];  // vpT: per-batch [1024][2048]
    const int batch = m0 >> 11, nb = m0 & 2047;
#pragma unroll
    for (int i = 0; i < 8; ++i) {
      const int c = i * 256 + t;
      const int lc = c >> 4, ch = c & 15;
      *(bf16x8*)(C + (long)batch * (2048 * 1024) + (long)(n0 + lc) * 2048 + nb + ch * 8) =
          *(const bf16x8*)(tt + lc * 256 + ((ch * 16) ^ ((lc & 7) << 4)));
    }
  }
}

// ---------------------------------------------------------------------------
extern "C" void kernel_launch(void* const* d_in, const int* in_sizes, int n_in,
                              void* d_out, int out_size, void* d_ws, size_t ws_size,
                              hipStream_t stream) {
  const int b = 4, n = 2048, d = 1024;
  const long nd  = (long)n * d;
  const long bn  = (long)b * n;
  const long bnd = bn * d;
  const long ddl = (long)d * d;
  const long nn  = (long)n * n;

  const float* q  = (const float*)d_in[0];
  const float* k  = (const float*)d_in[1];
  const float* v  = (const float*)d_in[2];
  const float* Wq = (const float*)d_in[3];
  const float* bq = (const float*)d_in[4];
  const float* Wk = (const float*)d_in[5];
  const float* bk = (const float*)d_in[6];
  const float* Wv = (const float*)d_in[7];
  const float* bv = (const float*)d_in[8];
  const float* Wo = (const float*)d_in[9];
  const float* bo = (const float*)d_in[10];

  bf16_t* ws  = (bf16_t*)d_ws;
  bf16_t* qB  = ws;              // bnd
  bf16_t* kB  = qB + bnd;        // bnd
  bf16_t* vB  = kB + bnd;        // bnd
  bf16_t* WqB = vB + bnd;        // ddl x4
  bf16_t* WkB = WqB + ddl;
  bf16_t* WvB = WkB + ddl;
  bf16_t* WoB = WvB + ddl;
  bf16_t* qpB = WoB + ddl;       // bnd
  bf16_t* kpB = qpB + bnd;       // bnd
  bf16_t* vpT = kpB + bnd;       // bnd (per-batch [d][n], from qkv3 epilogue)
  bf16_t* S   = vpT + bnd;       // b*nn
  bf16_t* yT  = S + (long)b * nn;// bnd
  const size_t need = (size_t)(7 * bnd + 4 * ddl + (long)b * nn) * 2;
  if (ws_size < need) return;

  dim3 blk(256);

  // fp32 -> bf16 converts: ONE launch, 7 segments
  CvtArgs ca;
  ca.src[0] = q;  ca.dst[0] = qB;  ca.n4[0] = bnd / 4;
  ca.src[1] = k;  ca.dst[1] = kB;  ca.n4[1] = bnd / 4;
  ca.src[2] = v;  ca.dst[2] = vB;  ca.n4[2] = bnd / 4;
  ca.src[3] = Wq; ca.dst[3] = WqB; ca.n4[3] = ddl / 4;
  ca.src[4] = Wk; ca.dst[4] = WkB; ca.n4[4] = ddl / 4;
  ca.src[5] = Wv; ca.dst[5] = WvB; ca.n4[5] = ddl / 4;
  ca.src[6] = Wo; ca.dst[6] = WoB; ca.n4[6] = ddl / 4;
  cvt_all<<<dim3(512, 7), blk, 0, stream>>>(ca);

  // fused QKV projections (BK=64 core): grid (8, 64, 3) = 1536 blocks
  Qkv3Args qa;
  qa.A[0] = qB; qa.W[0] = WqB; qa.bias[0] = bq; qa.C[0] = qpB;
  qa.A[1] = kB; qa.W[1] = WkB; qa.bias[1] = bk; qa.C[1] = kpB;
  qa.A[2] = vB; qa.W[2] = WvB; qa.bias[2] = bv; qa.C[2] = vpT;
  qkv3<<<dim3(d / 128, bn / 128, 3), blk, 0, stream>>>(qa, d, d);

  // scores: S[z] = qp[z] x kp[z]^T * (1/32), causal tile-skip
  gemm_bt<1, false, true, false><<<dim3(n / 128, n / 128, b), blk, 0, stream>>>(
      qpB, kpB, nullptr, S, n, d, 0.03125f, nd, nd, nn, 2);

  // causal softmax in place (bounded to the straddle tile)
  softmax_causal<<<dim3(n, b), blk, 0, stream>>>(S, n, nn);

  // yT[z] = vpT[z] x P[z]^T   (K bounded per N-tile by causality)
  gemm_bt<1, false, false, true><<<dim3(n / 128, d / 128, b), blk, 0, stream>>>(
      vpT, S, nullptr, yT, n, n, 1.f, nd, nn, nd, 2);

  // out = y2 x Wo^T + bo ; y2 flat == yT flat, fp32 out
  gemm_bt<0, true, false, false><<<dim3(d / 128, bn / 128, 1), blk, 0, stream>>>(
      yT, WoB, bo, (float*)d_out, d, d, 1.f, 0, 0, 0, 4);
}